// Round 1
// baseline (223.695 us; speedup 1.0000x reference)
//
#include <hip/hip_runtime.h>

// DepthToSpace: in [8, 64, 256, 256] f32 -> out [8, 4, 1024, 1024] f32
// out[b, s, h*4+r, w*4+c] = in[b, s*16 + r*4 + c, h, w]
//
// Output float4 at (row hh, pos) = { in[p0+c][h][pos] : c=0..3 }, a 4x4
// transpose of (channel x w). Each 4-lane quad:
//   - lane l loads float4 = channel p0+l, w = 4q..4q+3   (16 B/lane; per wave
//     instruction: 4 x 256 B contiguous segments, one per channel)
//   - 2-round __shfl_xor (masks 1,2) 4x4 transpose within the quad
//   - lane l stores output float4 at pos = 4q+l          (1 KiB/wave, contiguous)
// VMEM insts per wave per 2 KiB moved: 2 (was 5). No LDS, no barrier.

#define TOTAL_ELEMS (8 * 64 * 256 * 256)   // 33,554,432 floats
#define TOTAL_F4    (TOTAL_ELEMS / 4)      // 8,388,608 float4s = 2^23

__global__ __launch_bounds__(256) void DepthToSpace_8486855377460_kernel(
    const float4* __restrict__ in4, float4* __restrict__ out4) {
    int o = blockIdx.x * 256 + threadIdx.x;  // output float4 index (< 2^23)

    int l  = o & 3;            // lane-in-quad == element within output f4 group
    int q  = (o >> 2) & 63;    // w-block (w = 4q..4q+3 source columns)
    int hh = (o >> 8) & 1023;  // output row
    int s  = (o >> 18) & 3;    // split group
    int b  = o >> 20;          // batch

    int r = hh & 3;
    int h = hh >> 2;
    int p = (s << 4) + (r << 2) + l;  // this lane's source channel

    // in float4 index: ((b*64 + p) * 16384) + h*64 + q
    float4 m = in4[(((b << 6) + p) << 14) + (h << 6) + q];
    // lane l of the quad now holds M[l][c] = in[p0+l][h][4q+c]

    // ---- round 1: xor 1 (swap across column bit 0 / lane bit 0) ----
    int odd = l & 1;
    float s0 = odd ? m.x : m.y;
    float s1 = odd ? m.z : m.w;
    float r0 = __shfl_xor(s0, 1, 64);
    float r1 = __shfl_xor(s1, 1, 64);
    float4 n;
    n.x = odd ? r0  : m.x;
    n.y = odd ? m.y : r0;
    n.z = odd ? r1  : m.z;
    n.w = odd ? m.w : r1;

    // ---- round 2: xor 2 (swap across column bit 1 / lane bit 1) ----
    int hi = l & 2;
    s0 = hi ? n.x : n.z;
    s1 = hi ? n.y : n.w;
    r0 = __shfl_xor(s0, 2, 64);
    r1 = __shfl_xor(s1, 2, 64);
    float4 v;
    v.x = hi ? r0  : n.x;
    v.y = hi ? r1  : n.y;
    v.z = hi ? n.z : r0;
    v.w = hi ? n.w : r1;
    // lane l now holds R[l][c] = M[c][l] = in[p0+c][h][4q+l] = out f4 at pos 4q+l

    out4[o] = v;  // contiguous: wave writes 1 KiB
}

extern "C" void kernel_launch(void* const* d_in, const int* in_sizes, int n_in,
                              void* d_out, int out_size, void* d_ws, size_t ws_size,
                              hipStream_t stream) {
    const float4* x = (const float4*)d_in[0];
    float4* out = (float4*)d_out;
    dim3 block(256);
    dim3 grid(TOTAL_F4 / 256);  // 32768 blocks
    DepthToSpace_8486855377460_kernel<<<grid, block, 0, stream>>>(x, out);
}